// Round 1
// baseline (103.073 us; speedup 1.0000x reference)
//
#include <hip/hip_runtime.h>

#define NRES 384
#define NLIG 128
#define MCOPY 4
#define INC 384
#define MIDC 32
#define OUTC 128
#define NTOT 512

// ws layout (float offsets)
#define WS_RI   0           // [384][32]
#define WS_RJ   12288       // [384][32]
#define WS_LI   24576       // [m*128+r][32]
#define WS_LJ   40960       // [m*128+r][32]
#define WS_ARR  57344       // [384][y*128+o]
#define WS_ARL  1630208
#define WS_ALR  3203072
#define WS_ALL  4775936     // [m*128+il][y*128+o]
#define WS_WT   6873088     // 4 tensors x [x][y*128+o] (order rr,rl,lr,ll)
// total = 7397376 floats = 29.6 MB

// --- K0: transpose W[o][x][y] (o,1024) -> Wt[x][y*128+o] -------------------
__global__ __launch_bounds__(256) void k0_transposeW(
    const float* __restrict__ Wrr, const float* __restrict__ Wrl,
    const float* __restrict__ Wlr, const float* __restrict__ Wll,
    float* __restrict__ ws) {
  __shared__ float lds[128 * 33];
  int b = blockIdx.x;            // 0..127
  int tensor = b >> 5;
  int x = b & 31;
  const float* W = tensor == 0 ? Wrr : tensor == 1 ? Wrl : tensor == 2 ? Wlr : Wll;
  float* Wt = ws + WS_WT + tensor * 131072;
  int t = threadIdx.x;
  for (int k = 0; k < 16; ++k) {
    int idx = k * 256 + t;       // 0..4095
    int o = idx >> 5, y = idx & 31;
    lds[o * 33 + y] = W[o * 1024 + x * 32 + y];
  }
  __syncthreads();
  for (int k = 0; k < 16; ++k) {
    int idx = k * 256 + t;       // = y*128+o
    int y = idx >> 7, o = idx & 127;
    Wt[x * 4096 + idx] = lds[o * 33 + y];
  }
}

// --- K1: 1D projections ----------------------------------------------------
__global__ __launch_bounds__(64) void k1_proj(
    const float* __restrict__ rec, const float* __restrict__ lig,
    const float* __restrict__ rl1w, const float* __restrict__ rl1b,
    const float* __restrict__ rl2w, const float* __restrict__ rl2b,
    const float* __restrict__ ll1w, const float* __restrict__ ll1b,
    const float* __restrict__ ll2w, const float* __restrict__ ll2b,
    float* __restrict__ ws) {
  __shared__ float row[INC];
  int b = blockIdx.x;
  int t = threadIdx.x;
  const float* in;
  float *out1, *out2;
  const float *w1, *b1, *w2, *b2;
  if (b < NRES) {
    int r = b;
    in = rec + (size_t)r * INC;
    out1 = ws + WS_RI + r * 32;
    out2 = ws + WS_RJ + r * 32;
    w1 = rl1w; b1 = rl1b; w2 = rl2w; b2 = rl2b;
  } else {
    int r = b - NRES;            // 0..511 = m*128+nl
    in = lig + (size_t)r * INC;
    out1 = ws + WS_LI + r * 32;
    out2 = ws + WS_LJ + r * 32;
    w1 = ll1w; b1 = ll1b; w2 = ll2w; b2 = ll2b;
  }
  for (int k = t; k < INC; k += 64) row[k] = in[k];
  __syncthreads();
  int c = t & 31;
  const float* w = (t < 32 ? w1 : w2) + (size_t)c * INC;
  const float4* w4 = (const float4*)w;
  const float4* r4 = (const float4*)row;
  float acc = 0.f;
  for (int k = 0; k < INC / 4; ++k) {
    float4 a = r4[k], bb = w4[k];
    acc += a.x * bb.x + a.y * bb.y + a.z * bb.z + a.w * bb.w;
  }
  float bias = (t < 32 ? b1 : b2)[c];
  (t < 32 ? out1 : out2)[c] = acc + bias;
}

// --- K2: A[rows][y*128+o] = f[rows][x] @ Wt[x][y*128+o] --------------------
__global__ __launch_bounds__(256) void k2_makeA(float* __restrict__ ws) {
  __shared__ float wt[32 * 256];
  int b = blockIdx.x;            // 832 blocks
  int t = threadIdx.x;
  const float* fac;
  const float* Wt;
  float* A;
  int local;
  if (b < 192)      { local = b;       fac = ws + WS_RI; A = ws + WS_ARR; Wt = ws + WS_WT + 0 * 131072; }
  else if (b < 384) { local = b - 192; fac = ws + WS_RI; A = ws + WS_ARL; Wt = ws + WS_WT + 1 * 131072; }
  else if (b < 576) { local = b - 384; fac = ws + WS_RJ; A = ws + WS_ALR; Wt = ws + WS_WT + 2 * 131072; }
  else              { local = b - 576; fac = ws + WS_LI; A = ws + WS_ALL; Wt = ws + WS_WT + 3 * 131072; }
  int itile = local >> 4, ctile = local & 15;
  int i0 = itile * 32, cb = ctile * 256;
  for (int x = 0; x < 32; ++x) wt[x * 256 + t] = Wt[x * 4096 + cb + t];
  __syncthreads();
  float acc[32];
#pragma unroll
  for (int r = 0; r < 32; ++r) acc[r] = 0.f;
  for (int x = 0; x < 32; ++x) {
    float wv = wt[x * 256 + t];
#pragma unroll
    for (int r = 0; r < 32; ++r) acc[r] += fac[(i0 + r) * 32 + x] * wv;
  }
  for (int r = 0; r < 32; ++r) A[(size_t)(i0 + r) * 4096 + cb + t] = acc[r];
}

// --- K3a: rr / rl / lr quadrants -------------------------------------------
__global__ __launch_bounds__(256) void k3_top(
    const float* __restrict__ ws, float* __restrict__ out,
    const float* __restrict__ rrb, const float* __restrict__ rlb,
    const float* __restrict__ lrb) {
  __shared__ float A_lds[32 * 128];
  __shared__ float fac[128 * 33];
  int b = blockIdx.x;            // 1920 blocks
  int t = threadIdx.x;
  const float* Arow;
  const float* bias;
  float* outbase;
  int jstride;
  if (b < 1152) {                // rr: i in [0,384), 3 j-tiles of 128
    int i = b / 3, jt = b - 3 * i;
    int j0 = jt * 128;
    Arow = ws + WS_ARR + (size_t)i * 4096;
    const float* rj = ws + WS_RJ;
    for (int k = 0; k < 16; ++k) {
      int idx = k * 256 + t;
      int j = idx >> 5, y = idx & 31;
      fac[j * 33 + y] = rj[(j0 + j) * 32 + y];
    }
    bias = rrb;
    outbase = out + ((size_t)i * NTOT + j0) * OUTC;
    jstride = OUTC;
  } else if (b < 1536) {         // rl: i in [0,384), cols 384..511
    int i = b - 1152;
    Arow = ws + WS_ARL + (size_t)i * 4096;
    const float* lj = ws + WS_LJ;
    for (int k = 0; k < 16; ++k) {
      int idx = k * 256 + t;
      int j = idx >> 5, y = idx & 31;
      int s = j * 32 + y;
      fac[j * 33 + y] = 0.25f * (lj[s] + lj[4096 + s] + lj[8192 + s] + lj[12288 + s]);
    }
    bias = rlb;
    outbase = out + ((size_t)i * NTOT + NRES) * OUTC;
    jstride = OUTC;
  } else {                       // lr: col i, rows 384..511
    int i = b - 1536;
    Arow = ws + WS_ALR + (size_t)i * 4096;
    const float* li = ws + WS_LI;
    for (int k = 0; k < 16; ++k) {
      int idx = k * 256 + t;
      int j = idx >> 5, y = idx & 31;
      int s = j * 32 + y;
      fac[j * 33 + y] = 0.25f * (li[s] + li[4096 + s] + li[8192 + s] + li[12288 + s]);
    }
    bias = lrb;
    outbase = out + ((size_t)NRES * NTOT) * OUTC + (size_t)i * OUTC;
    jstride = NTOT * OUTC;
  }
  // stage A row: 4096 floats, float4-coalesced, linear
  float4* A4 = (float4*)A_lds;
  const float4* Ag = (const float4*)Arow;
  for (int k = 0; k < 4; ++k) A4[k * 256 + t] = Ag[k * 256 + t];
  __syncthreads();

  int og = t & 15, jg = t >> 4;
  int o0 = og * 8;
  float acc[8][8];
#pragma unroll
  for (int jj = 0; jj < 8; ++jj)
#pragma unroll
    for (int oo = 0; oo < 8; ++oo) acc[jj][oo] = 0.f;

  for (int y = 0; y < 32; ++y) {
    float4 a0 = *(const float4*)&A_lds[y * 128 + o0];
    float4 a1 = *(const float4*)&A_lds[y * 128 + o0 + 4];
#pragma unroll
    for (int jj = 0; jj < 8; ++jj) {
      float fv = fac[(jg * 8 + jj) * 33 + y];
      acc[jj][0] += fv * a0.x; acc[jj][1] += fv * a0.y;
      acc[jj][2] += fv * a0.z; acc[jj][3] += fv * a0.w;
      acc[jj][4] += fv * a1.x; acc[jj][5] += fv * a1.y;
      acc[jj][6] += fv * a1.z; acc[jj][7] += fv * a1.w;
    }
  }
  float4 b0 = *(const float4*)&bias[o0];
  float4 b1 = *(const float4*)&bias[o0 + 4];
#pragma unroll
  for (int jj = 0; jj < 8; ++jj) {
    int j = jg * 8 + jj;
    float* p = outbase + (size_t)j * jstride + o0;
    float4 v0, v1;
    v0.x = acc[jj][0] + b0.x; v0.y = acc[jj][1] + b0.y;
    v0.z = acc[jj][2] + b0.z; v0.w = acc[jj][3] + b0.w;
    v1.x = acc[jj][4] + b1.x; v1.y = acc[jj][5] + b1.y;
    v1.z = acc[jj][6] + b1.z; v1.w = acc[jj][7] + b1.w;
    *(float4*)p = v0;
    *(float4*)(p + 4) = v1;
  }
}

// --- K3b: ll quadrant (mean over m) ----------------------------------------
__global__ __launch_bounds__(256) void k3_ll(
    const float* __restrict__ ws, float* __restrict__ out,
    const float* __restrict__ llb) {
  __shared__ float A_lds[4 * 32 * 128];   // 64 KB
  __shared__ float fac[4 * 64 * 33];      // 33.8 KB
  int b = blockIdx.x;            // 256 blocks
  int il = b >> 1, jh = b & 1;
  int t = threadIdx.x;
  const float* All = ws + WS_ALL;
  const float* lj = ws + WS_LJ;
  float4* A4 = (float4*)A_lds;
  for (int k = 0; k < 16; ++k) {
    int idx = k * 256 + t;       // 0..4095 float4s
    int m = idx >> 10, rem = idx & 1023;
    A4[idx] = ((const float4*)(All + (size_t)(m * 128 + il) * 4096))[rem];
  }
  for (int k = 0; k < 32; ++k) {
    int idx = k * 256 + t;       // 0..8191
    int m = idx >> 11, rem = idx & 2047, j = rem >> 5, y = rem & 31;
    fac[(m * 64 + j) * 33 + y] = lj[((m * 128) + jh * 64 + j) * 32 + y];
  }
  __syncthreads();
  int og = t & 15, jg = t >> 4;
  int o0 = og * 8;
  float acc[4][8];
#pragma unroll
  for (int jj = 0; jj < 4; ++jj)
#pragma unroll
    for (int oo = 0; oo < 8; ++oo) acc[jj][oo] = 0.f;

  for (int m = 0; m < 4; ++m) {
    for (int y = 0; y < 32; ++y) {
      float4 a0 = *(const float4*)&A_lds[(m * 32 + y) * 128 + o0];
      float4 a1 = *(const float4*)&A_lds[(m * 32 + y) * 128 + o0 + 4];
#pragma unroll
      for (int jj = 0; jj < 4; ++jj) {
        float fv = fac[(m * 64 + jg * 4 + jj) * 33 + y];
        acc[jj][0] += fv * a0.x; acc[jj][1] += fv * a0.y;
        acc[jj][2] += fv * a0.z; acc[jj][3] += fv * a0.w;
        acc[jj][4] += fv * a1.x; acc[jj][5] += fv * a1.y;
        acc[jj][6] += fv * a1.z; acc[jj][7] += fv * a1.w;
      }
    }
  }
  float4 b0 = *(const float4*)&llb[o0];
  float4 b1 = *(const float4*)&llb[o0 + 4];
#pragma unroll
  for (int jj = 0; jj < 4; ++jj) {
    int j = jh * 64 + jg * 4 + jj;
    float* p = out + ((size_t)(NRES + il) * NTOT + NRES + j) * OUTC + o0;
    float4 v0, v1;
    v0.x = 0.25f * acc[jj][0] + b0.x; v0.y = 0.25f * acc[jj][1] + b0.y;
    v0.z = 0.25f * acc[jj][2] + b0.z; v0.w = 0.25f * acc[jj][3] + b0.w;
    v1.x = 0.25f * acc[jj][4] + b1.x; v1.y = 0.25f * acc[jj][5] + b1.y;
    v1.z = 0.25f * acc[jj][6] + b1.z; v1.w = 0.25f * acc[jj][7] + b1.w;
    *(float4*)p = v0;
    *(float4*)(p + 4) = v1;
  }
}

extern "C" void kernel_launch(void* const* d_in, const int* in_sizes, int n_in,
                              void* d_out, int out_size, void* d_ws, size_t ws_size,
                              hipStream_t stream) {
  const float* rec  = (const float*)d_in[0];
  const float* lig  = (const float*)d_in[1];
  const float* rl1w = (const float*)d_in[3];
  const float* rl1b = (const float*)d_in[4];
  const float* rl2w = (const float*)d_in[5];
  const float* rl2b = (const float*)d_in[6];
  const float* ll1w = (const float*)d_in[7];
  const float* ll1b = (const float*)d_in[8];
  const float* ll2w = (const float*)d_in[9];
  const float* ll2b = (const float*)d_in[10];
  const float* rrw  = (const float*)d_in[11];
  const float* rrb  = (const float*)d_in[12];
  const float* rlw  = (const float*)d_in[13];
  const float* rlb  = (const float*)d_in[14];
  const float* lrw  = (const float*)d_in[15];
  const float* lrb  = (const float*)d_in[16];
  const float* llw  = (const float*)d_in[17];
  const float* llb  = (const float*)d_in[18];
  float* out = (float*)d_out;
  float* ws  = (float*)d_ws;

  hipLaunchKernelGGL(k0_transposeW, dim3(128), dim3(256), 0, stream, rrw, rlw, lrw, llw, ws);
  hipLaunchKernelGGL(k1_proj, dim3(NRES + NTOT), dim3(64), 0, stream,
                     rec, lig, rl1w, rl1b, rl2w, rl2b, ll1w, ll1b, ll2w, ll2b, ws);
  hipLaunchKernelGGL(k2_makeA, dim3(832), dim3(256), 0, stream, ws);
  hipLaunchKernelGGL(k3_top, dim3(1920), dim3(256), 0, stream, ws, out, rrb, rlb, lrb);
  hipLaunchKernelGGL(k3_ll, dim3(256), dim3(256), 0, stream, ws, out, llb);
}